// Round 2
// baseline (818.030 us; speedup 1.0000x reference)
//
#include <hip/hip_runtime.h>
#include <cstddef>

#define NQ 4
#define KCODES 1024
#define CD 8
#define DIM 512
#define BATCH 16
#define TLEN 4096
#define TT 16
#define RPAD 17
#define NTHREADS 512

// workspace layout (floats)
#define WS_WIN  0
#define WS_WOUT (NQ * DIM * CD)
#define WS_CBN  (2 * NQ * DIM * CD)
// d_out layout (floats)
#define OUT_ZQ 0
#define OUT_CODES ((size_t)BATCH * DIM * TLEN)
#define OUT_LOSS (OUT_CODES + (size_t)NQ * BATCH * TLEN)

__global__ void rvq_zero(float* out) {
  out[OUT_LOSS] = 0.f;
  out[OUT_LOSS + 1] = 0.f;
}

// Normalize weight-norm weights and codebooks once into workspace.
// ws: w_in transposed [NQ][DIM][CD], w_out [NQ][DIM][CD], cb normalized [NQ][KCODES][CD]
__global__ void rvq_prep(const float* __restrict__ inv, const float* __restrict__ ing,
                         const float* __restrict__ outv, const float* __restrict__ outg,
                         const float* __restrict__ cb, float* __restrict__ ws) {
  const int blk = blockIdx.x, tid = threadIdx.x;
  if (blk < 32) {
    // in_proj rows: 32 rows of length 512, one block each
    const int i = blk >> 3, o = blk & 7;
    const float* v = inv + (size_t)(i * CD + o) * DIM;
    const float a = v[tid], b = v[tid + 256];
    float s = a * a + b * b;
    #pragma unroll
    for (int off = 32; off >= 1; off >>= 1) s += __shfl_xor(s, off);
    __shared__ float red[4];
    if ((tid & 63) == 0) red[tid >> 6] = s;
    __syncthreads();
    const float nrm = fmaxf(sqrtf(red[0] + red[1] + red[2] + red[3]), 1e-12f);
    const float g = ing[i * CD + o];
    ws[WS_WIN + (size_t)((i * DIM + tid) * CD) + o] = (g * a) / nrm;
    ws[WS_WIN + (size_t)((i * DIM + tid + 256) * CD) + o] = (g * b) / nrm;
  } else {
    const int rid = (blk - 32) * 256 + tid;   // 0..6143
    if (rid < NQ * DIM) {
      // out_proj rows: 2048 rows of length 8
      const float* v = outv + (size_t)rid * CD;
      float vv[8]; float n2 = 0.f;
      #pragma unroll
      for (int o = 0; o < 8; ++o) { vv[o] = v[o]; n2 += vv[o] * vv[o]; }
      const float nrm = fmaxf(sqrtf(n2), 1e-12f);
      const float g = outg[rid];
      #pragma unroll
      for (int o = 0; o < 8; ++o) ws[WS_WOUT + (size_t)rid * CD + o] = (g * vv[o]) / nrm;
    } else {
      // codebook rows: 4096 rows of length 8
      const int k = rid - NQ * DIM;
      const float* v = cb + (size_t)k * CD;
      float vv[8]; float n2 = 0.f;
      #pragma unroll
      for (int o = 0; o < 8; ++o) { vv[o] = v[o]; n2 += vv[o] * vv[o]; }
      const float nrm = fmaxf(sqrtf(n2), 1e-12f);
      #pragma unroll
      for (int o = 0; o < 8; ++o) ws[WS_CBN + (size_t)k * CD + o] = vv[o] / nrm;
    }
  }
}

// Fused RVQ. TT=16 tokens/block, res tile [512][17] (pad -> 2-way bank alias = free).
// LDS total 40448 B -> 4 blocks/CU x 8 waves = 32 waves/CU (100% occupancy).
__launch_bounds__(NTHREADS, 8)
__global__ void rvq_main(const float* __restrict__ z,
                         const float* __restrict__ b_in, const float* __restrict__ b_out,
                         const float* __restrict__ cb, const float* __restrict__ ws,
                         float* __restrict__ out) {
  __shared__ float res[DIM * RPAD];      // 8704 floats = 34816 B
  __shared__ float part[8 * TT * 9];     // 1152 floats =  4608 B
  __shared__ float sc[8 * TT];           //  128 floats =   512 B
  __shared__ int   idl[8 * TT];          //  128 ints   =   512 B

  const int tid = threadIdx.x;
  const int bb = blockIdx.x >> 8;            // batch index
  const int t0 = (blockIdx.x & 255) * TT;    // token tile start
  const float* zb = z + (size_t)bb * DIM * TLEN + t0;

  // ---- stage residual tile (global float4, coalesced along T; scalar LDS writes due to pad)
  {
    const int q = tid & 3, d0 = tid >> 2;
    #pragma unroll
    for (int p = 0; p < 4; ++p) {
      const int d = d0 + p * 128;
      const float4 v = *(const float4*)(zb + (size_t)d * TLEN + q * 4);
      float* rp = res + d * RPAD + q * 4;
      rp[0] = v.x; rp[1] = v.y; rp[2] = v.z; rp[3] = v.w;
    }
  }
  __syncthreads();

  const int t  = tid & 15;   // token within tile
  const int dc = tid >> 4;   // d-chunk 0..31 (16 rows each); also code-chunk (32 codes each)
  const int w  = tid >> 6;   // wave 0..7
  float loss_acc = 0.f;

  for (int i = 0; i < NQ; ++i) {
    // ---- in_proj: partial dots over this thread's 16-row d-chunk
    float acc[8] = {0,0,0,0,0,0,0,0};
    {
      const float* wp = ws + WS_WIN + (size_t)(i * DIM + dc * 16) * CD;
      const float* rp = res + dc * 16 * RPAD + t;
      #pragma unroll
      for (int j = 0; j < 16; ++j) {
        const float r = rp[j * RPAD];
        const float4 w0 = *(const float4*)(wp + j * 8);
        const float4 w1 = *(const float4*)(wp + j * 8 + 4);
        acc[0] += w0.x * r; acc[1] += w0.y * r; acc[2] += w0.z * r; acc[3] += w0.w * r;
        acc[4] += w1.x * r; acc[5] += w1.y * r; acc[6] += w1.z * r; acc[7] += w1.w * r;
      }
    }
    // reduce 4 chunks within wave (lane = (dc&3)*16 + t)
    #pragma unroll
    for (int o = 0; o < 8; ++o) {
      acc[o] += __shfl_xor(acc[o], 16);
      acc[o] += __shfl_xor(acc[o], 32);
    }
    if ((tid & 63) < 16) {
      float* pp = part + (w * TT + t) * 9;
      #pragma unroll
      for (int o = 0; o < 8; ++o) pp[o] = acc[o];
    }
    __syncthreads();

    // ---- every thread builds e for its token (sum 8 wave partials + bias)
    float e[8];
    #pragma unroll
    for (int o = 0; o < 8; ++o) e[o] = b_in[i * CD + o];
    #pragma unroll
    for (int w2 = 0; w2 < 8; ++w2) {
      const float* pp = part + (w2 * TT + t) * 9;
      #pragma unroll
      for (int o = 0; o < 8; ++o) e[o] += pp[o];
    }
    float ne2 = 0.f;
    #pragma unroll
    for (int o = 0; o < 8; ++o) ne2 += e[o] * e[o];
    const float ne = sqrtf(ne2);

    // ---- argmax over this thread's 32-code chunk.
    // argmax_k dot(en, cn_k) == argmax_k dot(e, cn_k): skip normalizing e here.
    float best = -1e30f; int bk = 0;
    {
      const float* cp = ws + WS_CBN + (size_t)(i * KCODES + dc * 32) * CD;
      #pragma unroll 4
      for (int k = 0; k < 32; ++k) {
        const float4 c0 = *(const float4*)(cp + k * 8);
        const float4 c1 = *(const float4*)(cp + k * 8 + 4);
        const float s = e[0]*c0.x + e[1]*c0.y + e[2]*c0.z + e[3]*c0.w
                      + e[4]*c1.x + e[5]*c1.y + e[6]*c1.z + e[7]*c1.w;
        if (s > best) { best = s; bk = dc * 32 + k; }
      }
    }
    // wave-level argmax over 4 chunks (ascending k; ties -> smaller k)
    #pragma unroll
    for (int off = 16; off <= 32; off <<= 1) {
      const float s2 = __shfl_xor(best, off);
      const int   k2 = __shfl_xor(bk, off);
      if (s2 > best || (s2 == best && k2 < bk)) { best = s2; bk = k2; }
    }
    if ((tid & 63) < 16) { sc[w * TT + t] = best; idl[w * TT + t] = bk; }
    __syncthreads();
    // cross-wave argmax (8 candidates, redundant in every thread)
    best = -1e30f; bk = KCODES;
    #pragma unroll
    for (int w2 = 0; w2 < 8; ++w2) {
      const float s2 = sc[w2 * TT + t];
      const int   k2 = idl[w2 * TT + t];
      if (s2 > best || (s2 == best && k2 < bk)) { best = s2; bk = k2; }
    }
    if (tid < TT) {
      out[OUT_CODES + (size_t)(i * BATCH + bb) * TLEN + t0 + tid] = (float)bk;
    }

    // ---- raw code vector + loss (one accumulator per token: dc==0 threads)
    float qv[8];
    {
      const float* qp = cb + (size_t)(i * KCODES + bk) * CD;
      const float4 q0 = *(const float4*)qp;
      const float4 q1 = *(const float4*)(qp + 4);
      qv[0]=q0.x; qv[1]=q0.y; qv[2]=q0.z; qv[3]=q0.w;
      qv[4]=q1.x; qv[5]=q1.y; qv[6]=q1.z; qv[7]=q1.w;
    }
    if (dc == 0) {
      float s = 0.f;
      #pragma unroll
      for (int o = 0; o < 8; ++o) { const float d2 = e[o] - qv[o]; s += d2 * d2; }
      loss_acc += s;
    }

    // ---- rotation trick (4 divides total; ene = |e|^2 * rne analytically)
    const float rne = 1.f / fmaxf(ne, 1e-12f);
    float nq2 = 0.f;
    #pragma unroll
    for (int o = 0; o < 8; ++o) nq2 += qv[o] * qv[o];
    const float nq = sqrtf(nq2);
    const float rq = 1.f / fmaxf(nq, 1e-12f);
    float ru[8]; float nr2 = 0.f;
    #pragma unroll
    for (int o = 0; o < 8; ++o) { ru[o] = e[o] * rne + qv[o] * rq; nr2 += ru[o] * ru[o]; }
    const float rr = 1.f / fmaxf(sqrtf(nr2), 1e-12f);
    const float scale = nq / fmaxf(ne, 1e-8f);
    float re = 0.f;
    #pragma unroll
    for (int o = 0; o < 8; ++o) { ru[o] *= rr; re += ru[o] * e[o]; }
    const float ene = ne2 * rne;
    // overwrite e with z_rot (frees registers)
    #pragma unroll
    for (int o = 0; o < 8; ++o)
      e[o] = scale * (e[o] - 2.f * ru[o] * re + 2.f * (qv[o] * rq) * ene);

    // ---- out_proj + in-place residual update on this thread's d-chunk
    {
      const float* wp2 = ws + WS_WOUT + (size_t)(i * DIM + dc * 16) * CD;
      const float* bp2 = b_out + i * DIM + dc * 16;
      float* rp2 = res + dc * 16 * RPAD + t;
      #pragma unroll
      for (int j = 0; j < 16; ++j) {
        const float4 w0 = *(const float4*)(wp2 + j * 8);
        const float4 w1 = *(const float4*)(wp2 + j * 8 + 4);
        float v = bp2[j];
        v += w0.x*e[0] + w0.y*e[1] + w0.z*e[2] + w0.w*e[3]
           + w1.x*e[4] + w1.y*e[5] + w1.z*e[6] + w1.w*e[7];
        rp2[j * RPAD] -= v;
      }
    }
    __syncthreads();
  }

  // ---- output z_q = z - final residual
  {
    const int q = tid & 3, d0 = tid >> 2;
    float* ob = out + OUT_ZQ + (size_t)bb * DIM * TLEN + t0;
    #pragma unroll
    for (int p = 0; p < 4; ++p) {
      const int d = d0 + p * 128;
      float4 v = *(const float4*)(zb + (size_t)d * TLEN + q * 4);
      const float* rp = res + d * RPAD + q * 4;
      v.x -= rp[0]; v.y -= rp[1]; v.z -= rp[2]; v.w -= rp[3];
      *(float4*)(ob + (size_t)d * TLEN + q * 4) = v;
    }
  }

  // ---- loss reduce: nonzero only in lanes 0..15 of wave 0
  loss_acc += __shfl_xor(loss_acc, 8);
  loss_acc += __shfl_xor(loss_acc, 4);
  loss_acc += __shfl_xor(loss_acc, 2);
  loss_acc += __shfl_xor(loss_acc, 1);
  if (tid == 0) {
    const float lv = loss_acc * (1.f / ((float)CD * TLEN * BATCH));
    atomicAdd(out + OUT_LOSS, lv);       // commitment_loss
    atomicAdd(out + OUT_LOSS + 1, lv);   // codebook_loss (identical forward value)
  }
}

extern "C" void kernel_launch(void* const* d_in, const int* in_sizes, int n_in,
                              void* d_out, int out_size, void* d_ws, size_t ws_size,
                              hipStream_t stream) {
  const float* z    = (const float*)d_in[0];
  const float* inv  = (const float*)d_in[1];
  const float* ing  = (const float*)d_in[2];
  const float* inb  = (const float*)d_in[3];
  const float* outv = (const float*)d_in[4];
  const float* outg = (const float*)d_in[5];
  const float* outb = (const float*)d_in[6];
  const float* cbp  = (const float*)d_in[7];
  float* out = (float*)d_out;
  float* ws  = (float*)d_ws;

  hipLaunchKernelGGL(rvq_zero, dim3(1), dim3(1), 0, stream, out);
  hipLaunchKernelGGL(rvq_prep, dim3(56), dim3(256), 0, stream,
                     inv, ing, outv, outg, cbp, ws);
  hipLaunchKernelGGL(rvq_main, dim3(BATCH * (TLEN / TT)), dim3(NTHREADS),
                     0, stream, z, inb, outb, cbp, ws, out);
}